// Round 7
// baseline (445.458 us; speedup 1.0000x reference)
//
#include <hip/hip_runtime.h>
#include <math.h>

typedef unsigned short u16;
typedef short s16x8 __attribute__((ext_vector_type(8)));  // 8 bf16 lanes (4 VGPRs)
typedef float f32x4 __attribute__((ext_vector_type(4)));

// B=2, S=2048, D=2048, H=16, HD=128; qkv row width = 6144
#define ATTN_SCALE 0.08838834764831845f
#define NEG_BIG -1.0e30f

__device__ __forceinline__ u16 f2bf(float f) {
  union { float f; unsigned u; } c; c.f = f;
  return (u16)((c.u + 0x7fffu + ((c.u >> 16) & 1u)) >> 16);  // RNE
}
__device__ __forceinline__ float bf2f(u16 v) {
  union { unsigned u; float f; } c; c.u = ((unsigned)v) << 16;
  return c.f;
}
__device__ __forceinline__ f32x4 mfma16(s16x8 a, s16x8 b, f32x4 c) {
  return __builtin_amdgcn_mfma_f32_16x16x32_bf16(a, b, c, 0, 0, 0);
}
// async global->LDS DMA, 16 B/lane; LDS dest = wave-uniform base + lane*16
__device__ __forceinline__ void gl_lds16(const u16* g, u16* l) {
  __builtin_amdgcn_global_load_lds(
      (const __attribute__((address_space(1))) unsigned int*)g,
      (__attribute__((address_space(3))) unsigned int*)l, 16, 0, 0);
}

// -------- fp32 -> bf16 elementwise cast (float4 vectorized) -------------
__global__ __launch_bounds__(256) void k_cast(const float* __restrict__ in,
                                              u16* __restrict__ out, int n4) {
  const int i = blockIdx.x * 256 + threadIdx.x;
  if (i >= n4) return;
  const float4 v = ((const float4*)in)[i];
  ushort4 o;
  o.x = f2bf(v.x); o.y = f2bf(v.y); o.z = f2bf(v.z); o.w = f2bf(v.w);
  ((ushort4*)out)[i] = o;
}

// -------- fp32 [R][C] -> bf16 out[C][R] transpose+cast ------------------
__global__ __launch_bounds__(256) void k_transpose_cast(const float* __restrict__ in,
                                                        u16* __restrict__ out,
                                                        int R, int C) {
  __shared__ __attribute__((aligned(16))) u16 tile[32][33];
  const int c0 = blockIdx.x * 32, r0 = blockIdx.y * 32;
  const int tx = threadIdx.x, ty = threadIdx.y;
#pragma unroll
  for (int i = 0; i < 4; ++i)
    tile[ty + 8 * i][tx] = f2bf(in[(r0 + ty + 8 * i) * C + c0 + tx]);
  __syncthreads();
#pragma unroll
  for (int i = 0; i < 4; ++i)
    out[(c0 + ty + 8 * i) * R + r0 + tx] = tile[tx][ty + 8 * i];
}

// ---------------- V -> V^T per (b,h): vt[bh][d][s] = qkv_v[b,s,h,d] ------
__global__ __launch_bounds__(256) void k_vtrans(const u16* __restrict__ qkv,
                                                u16* __restrict__ vt) {
  __shared__ __attribute__((aligned(16))) u16 tile[32][33];
  const int bh = blockIdx.z, b = bh >> 4, h = bh & 15;
  const int s0 = blockIdx.x * 32, d0 = blockIdx.y * 32;
  const int tx = threadIdx.x, ty = threadIdx.y;
#pragma unroll
  for (int i = 0; i < 4; ++i) {
    const int s = s0 + ty + 8 * i;
    tile[ty + 8 * i][tx] = qkv[(b * 2048 + s) * 6144 + 4096 + h * 128 + d0 + tx];
  }
  __syncthreads();
#pragma unroll
  for (int i = 0; i < 4; ++i) {
    const int d = d0 + ty + 8 * i;
    vt[bh * 262144 + d * 2048 + s0 + tx] = tile[tx][ty + 8 * i];
  }
}

// ---------------- RoPE in-place on Q and K sections of qkv (bf16) -------
__global__ __launch_bounds__(256) void k_rope(u16* __restrict__ qkv) {
  const int id = blockIdx.x * 256 + threadIdx.x;  // 8,388,608 threads
  const int j = id & 63;
  const int h = (id >> 6) & 15;
  const int sec = (id >> 10) & 1;
  const int m = id >> 11;  // b*2048+s
  const int s = m & 2047;
  const int base = m * 6144 + sec * 2048 + h * 128 + j;
  const float q0 = bf2f(qkv[base]);
  const float q1 = bf2f(qkv[base + 64]);
  const float inv = exp2f((float)j * -0.20762050593046014f);  // 10000^(-j/64)
  const float ang = (float)s * inv;
  float c, sn;
  sincosf(ang, &sn, &c);  // sincosf(x, SIN*, COS*) — sin FIRST
  qkv[base]      = f2bf(q0 * c - q1 * sn);
  qkv[base + 64] = f2bf(q1 * c + q0 * sn);
}

// ------- GEMM (m97 structure): C[M][N] = A[M][K] * BT[N][K]^T -----------
// kept for the fp32-A fallback path.
template <bool A_F32, typename OUT_T>
__global__ __launch_bounds__(256) void k_gemm_lds(const void* __restrict__ Ap, int lda,
                                                  const u16* __restrict__ BT,
                                                  OUT_T* __restrict__ C, int ldc,
                                                  int K) {
  __shared__ __attribute__((aligned(16))) u16 As[128 * 32];
  __shared__ __attribute__((aligned(16))) u16 Bs[128 * 32];
  const int tid = threadIdx.x;
  const int lane = tid & 63, wave = tid >> 6;
  const int lm = lane & 15, quad = lane >> 4;
  const int wm = wave >> 1, wn = wave & 1;
  const int m0 = blockIdx.y * 128, n0 = blockIdx.x * 128;
  const int srow = lane >> 2, scol = (lane & 3) * 8;  // staging map

  const f32x4 fzero = {0.f, 0.f, 0.f, 0.f};
  f32x4 acc[4][4];
#pragma unroll
  for (int i = 0; i < 4; ++i)
#pragma unroll
    for (int j = 0; j < 4; ++j) acc[i][j] = fzero;

  for (int k0 = 0; k0 < K; k0 += 32) {
    __syncthreads();
    if constexpr (A_F32) {
      const float* Af = (const float*)Ap;
#pragma unroll
      for (int i = 0; i < 2; ++i) {
        const int seg = tid + 256 * i;
        const int row = seg >> 2, c8 = (seg & 3) * 8;
        const float4 u = *(const float4*)&Af[(m0 + row) * lda + k0 + c8];
        const float4 w = *(const float4*)&Af[(m0 + row) * lda + k0 + c8 + 4];
        uint4 pk;
        pk.x = (unsigned)f2bf(u.x) | ((unsigned)f2bf(u.y) << 16);
        pk.y = (unsigned)f2bf(u.z) | ((unsigned)f2bf(u.w) << 16);
        pk.z = (unsigned)f2bf(w.x) | ((unsigned)f2bf(w.y) << 16);
        pk.w = (unsigned)f2bf(w.z) | ((unsigned)f2bf(w.w) << 16);
        *(uint4*)&As[row * 32 + c8] = pk;
      }
#pragma unroll
      for (int j = 0; j < 2; ++j) {
        const int rb = wave * 32 + j * 16;
        gl_lds16(&BT[(n0 + rb + srow) * K + k0 + scol], &Bs[rb * 32]);
      }
    } else {
      const u16* Ab = (const u16*)Ap;
#pragma unroll
      for (int j = 0; j < 2; ++j) {
        const int rb = wave * 32 + j * 16;
        gl_lds16(&Ab[(m0 + rb + srow) * lda + k0 + scol], &As[rb * 32]);
        gl_lds16(&BT[(n0 + rb + srow) * K + k0 + scol], &Bs[rb * 32]);
      }
    }
    __syncthreads();  // drains vmcnt (DMA) + lgkmcnt before reads

    s16x8 af[4], bfr[4];
#pragma unroll
    for (int t = 0; t < 4; ++t) {
      af[t]  = *(const s16x8*)&As[(wm * 64 + t * 16 + lm) * 32 + quad * 8];
      bfr[t] = *(const s16x8*)&Bs[(wn * 64 + t * 16 + lm) * 32 + quad * 8];
    }
#pragma unroll
    for (int mt = 0; mt < 4; ++mt)
#pragma unroll
      for (int nt = 0; nt < 4; ++nt)
        acc[mt][nt] = mfma16(af[mt], bfr[nt], acc[mt][nt]);
  }
#pragma unroll
  for (int mt = 0; mt < 4; ++mt)
#pragma unroll
    for (int nt = 0; nt < 4; ++nt)
#pragma unroll
      for (int r = 0; r < 4; ++r) {
        const float v = acc[mt][nt][r];
        const int idx = (m0 + wm * 64 + mt * 16 + quad * 4 + r) * ldc +
                        n0 + wn * 64 + nt * 16 + lm;
        if constexpr (sizeof(OUT_T) == 2) C[idx] = f2bf(v);
        else                              C[idx] = v;
      }
}

// ------- 256x128 GEMM v4 (3-deep rotating): kept for the W_o GEMM -------
template <typename OUT_T>
__global__ __launch_bounds__(512, 2) void k_gemm256(const u16* __restrict__ A, int lda,
                                                    const u16* __restrict__ BT, int ldb,
                                                    OUT_T* __restrict__ C, int ldc) {
  __shared__ __attribute__((aligned(16))) u16 As[3][2][256 * 32];  // 96 KB
  __shared__ __attribute__((aligned(16))) u16 Bs[3][2][128 * 32];  // 48 KB
  const int tid = threadIdx.x;
  const int lane = tid & 63, wave = tid >> 6;
  const int lm = lane & 15, quad = lane >> 4;
  const int wm = wave >> 1, wn = wave & 1;  // 4M x 2N wave grid

  int bid = (blockIdx.x & 7) * (gridDim.x >> 3) + (blockIdx.x >> 3);
  const int m0 = (bid & 15) * 256;  // M=4096 -> 16 tiles
  const int n0 = (bid >> 4) * 128;

  const int srow = lane >> 2, schunk = (lane & 3) * 8;
  auto stage_h = [&](int t, int h) {
    const int bi = t % 3;
    const int k0 = t * 64 + h * 32 + schunk;
    gl_lds16(&BT[(n0 + wave * 16 + srow) * ldb + k0],
             &Bs[bi][h][(wave * 16) * 32]);
    gl_lds16(&A[(m0 + wave * 32 + srow) * lda + k0],
             &As[bi][h][(wave * 32) * 32]);
    gl_lds16(&A[(m0 + wave * 32 + 16 + srow) * lda + k0],
             &As[bi][h][(wave * 32 + 16) * 32]);
  };

  const f32x4 fzero = {0.f, 0.f, 0.f, 0.f};
  f32x4 acc[4][4];
#pragma unroll
  for (int i = 0; i < 4; ++i)
#pragma unroll
    for (int j = 0; j < 4; ++j) acc[i][j] = fzero;

  stage_h(0, 0); stage_h(0, 1); stage_h(1, 0); stage_h(1, 1);
  asm volatile("s_waitcnt vmcnt(9)" ::: "memory");
  asm volatile("s_barrier" ::: "memory");

  for (int c = 0; c < 32; ++c) {
    const int bi = c % 3;
#pragma unroll
    for (int p = 0; p < 2; ++p) {
      s16x8 bfr[4], afr[4];
#pragma unroll
      for (int nt = 0; nt < 4; ++nt)
        bfr[nt] = *(const s16x8*)
            &Bs[bi][p][(wn * 64 + nt * 16 + lm) * 32 + quad * 8];
#pragma unroll
      for (int i = 0; i < 4; ++i)
        afr[i] = *(const s16x8*)
            &As[bi][p][(wm * 64 + i * 16 + lm) * 32 + quad * 8];
      if (c < 30) stage_h(c + 2, p);
      if (c < 30) {
        asm volatile("s_waitcnt vmcnt(9)" ::: "memory");
      } else if (c == 30) {
        if (p == 0) asm volatile("s_waitcnt vmcnt(6)" ::: "memory");
        else        asm volatile("s_waitcnt vmcnt(3)" ::: "memory");
      } else {
        if (p == 0) asm volatile("s_waitcnt vmcnt(0)" ::: "memory");
      }
      asm volatile("s_barrier" ::: "memory");
      __builtin_amdgcn_s_setprio(1);
#pragma unroll
      for (int i = 0; i < 4; ++i)
#pragma unroll
        for (int nt = 0; nt < 4; ++nt)
          acc[i][nt] = mfma16(afr[i], bfr[nt], acc[i][nt]);
      __builtin_amdgcn_s_setprio(0);
      if (!(c == 31 && p == 1)) asm volatile("s_barrier" ::: "memory");
    }
  }

#pragma unroll
  for (int i = 0; i < 4; ++i)
#pragma unroll
    for (int nt = 0; nt < 4; ++nt)
#pragma unroll
      for (int r = 0; r < 4; ++r) {
        const float v = acc[i][nt][r];
        const int idx = (m0 + wm * 64 + i * 16 + quad * 4 + r) * ldc +
                        n0 + wn * 64 + nt * 16 + lm;
        if constexpr (sizeof(OUT_T) == 2) C[idx] = f2bf(v);
        else                              C[idx] = v;
      }
}

// ------- 256x256 GEMM v5: 512 B/MFMA geometry + fine 16-MFMA phases -----
// C[M][N] = A[M][K]*BT[N][K]^T, bf16 in/out. K=2048 = 32 tiles of BK=64
// (2 ks-units of 32). 8 waves 2Mx4N, wave tile 128x64 (the 512 B/MFMA
// geometry: reads 384 + DMA 128 B per MFMA -> LDS-BW ceiling ~60% at
// 256 B/cy). LDS 128 KiB = [2 dbuf][2 ks] x (A[256][32] + B[256][32]).
// Phase (ks,mh): {4 A-reads (+4 B-reads at mh0, B regs persist the pair)
// -> stage ONE 16 KB unit (2 gl_lds/wave) -> vmcnt(10) -> barrier ->
// setprio 16 MFMA setprio -> barrier}. Cross-wave stagger (per-wave lgkm
// waits land inside the MFMA cluster) overlaps LDS and matrix pipes.
// Unit stream at tile c: q0:(c+1,A,ks1) q1:(c+2,B,ks0) q2:(c+2,A,ks0)
// q3:(c+2,B,ks1). Stage->first-read distance 6-7 phases (~3000 cy >> HBM
// latency). WAR: each slot staged >=1 barrier after its last read
// (read-last: B0@q0, A0@q1, B1@q2, A1@q3). Ledger (2 loads/unit): steady
// outstanding after wait = 5 units -> vmcnt(10) certifies just-in-time;
// tail drain 10/8/8/4 (c=30), 4/0/0/- (c=31). Prologue stages 7 units in
// stream order then vmcnt(10) (certifies tile0 B0,A0).
__global__ __launch_bounds__(512, 2) void k_gemm256b(const u16* __restrict__ A, int lda,
                                                     const u16* __restrict__ BT, int ldb,
                                                     u16* __restrict__ C, int ldc) {
  __shared__ __attribute__((aligned(16))) u16 As[2][2][256 * 32];  // 64 KB
  __shared__ __attribute__((aligned(16))) u16 Bs[2][2][256 * 32];  // 64 KB
  const int tid = threadIdx.x;
  const int lane = tid & 63, wave = tid >> 6;
  const int lm = lane & 15, quad = lane >> 4;
  const int wm = wave >> 2, wn = wave & 3;  // 2M x 4N wave grid

  // XCD swizzle (grid=384, %8==0 -> bijective); column-major tile map.
  int bid = (blockIdx.x & 7) * (gridDim.x >> 3) + (blockIdx.x >> 3);
  const int m0 = (bid & 15) * 256;  // M=4096 -> 16 tiles
  const int n0 = (bid >> 4) * 256;  // N=6144 -> 24 tiles

  // stage unit (tile t, matrix, ks): 256 rows x 32 k, 2 gl_lds per wave
  const int srow = lane >> 2, schunk = (lane & 3) * 8;
  auto stage_u = [&](int t, int isA, int ks) {
    const int k0 = t * 64 + ks * 32 + schunk;
#pragma unroll
    for (int j = 0; j < 2; ++j) {
      const int r0 = wave * 32 + j * 16;
      if (isA) gl_lds16(&A[(m0 + r0 + srow) * lda + k0], &As[t & 1][ks][r0 * 32]);
      else     gl_lds16(&BT[(n0 + r0 + srow) * ldb + k0], &Bs[t & 1][ks][r0 * 32]);
    }
  };

  const f32x4 fzero = {0.f, 0.f, 0.f, 0.f};
  f32x4 acc[8][4];
#pragma unroll
  for (int i = 0; i < 8; ++i)
#pragma unroll
    for (int j = 0; j < 4; ++j) acc[i][j] = fzero;

  // prologue: 7 units in stream order; certify tile0 {B0,A0}
  stage_u(0, 0, 0); stage_u(0, 1, 0); stage_u(0, 0, 1); stage_u(0, 1, 1);
  stage_u(1, 0, 0); stage_u(1, 1, 0); stage_u(1, 0, 1);
  asm volatile("s_waitcnt vmcnt(10)" ::: "memory");
  asm volatile("s_barrier" ::: "memory");

  for (int c = 0; c < 32; ++c) {
    const int buf = c & 1;
    s16x8 bfr[4];
#pragma unroll
    for (int q = 0; q < 4; ++q) {
      const int ks = q >> 1, mh = q & 1;
      // ---- fragment reads: B at mh0 (persist the pair), A every phase
      if (mh == 0) {
#pragma unroll
        for (int nt = 0; nt < 4; ++nt)
          bfr[nt] = *(const s16x8*)
              &Bs[buf][ks][(wn * 64 + nt * 16 + lm) * 32 + quad * 8];
      }
      s16x8 afr[4];
#pragma unroll
      for (int i = 0; i < 4; ++i)
        afr[i] = *(const s16x8*)
            &As[buf][ks][(wm * 128 + mh * 64 + i * 16 + lm) * 32 + quad * 8];
      // ---- stage one unit per phase (stream; see header comment)
      if (q == 0)      { if (c <= 30) stage_u(c + 1, 1, 1); }
      else if (q == 1) { if (c <= 29) stage_u(c + 2, 0, 0); }
      else if (q == 2) { if (c <= 29) stage_u(c + 2, 1, 0); }
      else             { if (c <= 29) stage_u(c + 2, 0, 1); }
      // ---- counted certification (steady vmcnt(10); exact tail drain)
      if (c < 30) {
        asm volatile("s_waitcnt vmcnt(10)" ::: "memory");
      } else if (c == 30) {
        if (q == 0)      asm volatile("s_waitcnt vmcnt(10)" ::: "memory");
        else if (q == 3) asm volatile("s_waitcnt vmcnt(4)" ::: "memory");
        else             asm volatile("s_waitcnt vmcnt(8)" ::: "memory");
      } else {
        if (q == 0)      asm volatile("s_waitcnt vmcnt(4)" ::: "memory");
        else if (q < 3)  asm volatile("s_waitcnt vmcnt(0)" ::: "memory");
      }
      asm volatile("s_barrier" ::: "memory");
      // ---- 16-MFMA cluster (lgkm waits land per-wave inside -> stagger)
      __builtin_amdgcn_s_setprio(1);
#pragma unroll
      for (int i = 0; i < 4; ++i)
#pragma unroll
        for (int nt = 0; nt < 4; ++nt)
          acc[mh * 4 + i][nt] = mfma16(afr[i], bfr[nt], acc[mh * 4 + i][nt]);
      __builtin_amdgcn_s_setprio(0);
      if (!(c == 31 && q == 3)) asm volatile("s_barrier" ::: "memory");
    }
  }

  // epilogue: C write (fragment->C mapping harness-verified rounds 3-6)
#pragma unroll
  for (int mt = 0; mt < 8; ++mt)
#pragma unroll
    for (int nt = 0; nt < 4; ++nt)
#pragma unroll
      for (int r = 0; r < 4; ++r)
        C[(m0 + wm * 128 + mt * 16 + quad * 4 + r) * ldc +
          n0 + wn * 64 + nt * 16 + lm] = f2bf(acc[mt][nt][r]);
}

// ---------------- causal flash attention, v4 ----------------------------
__global__ __launch_bounds__(256) void k_attn(u16* __restrict__ qkv,
                                              const u16* __restrict__ vt) {
  __shared__ __attribute__((aligned(16))) u16 Ks[2][64 * 128];  // 2x16 KB, swizzled
  __shared__ __attribute__((aligned(16))) u16 Vs[2][128 * 64];  // 2x16 KB, swizzled
  __shared__ __attribute__((aligned(16))) u16 Ps[4 * 16 * 72];  //    9 KB
  const int bh = blockIdx.x, pair = blockIdx.y;
  const int b = bh >> 4, h = bh & 15;
  const int tid = threadIdx.x;
  const int lane = tid & 63, wave = tid >> 6;
  const int lm = lane & 15, quad = lane >> 4;
  const int pbase = wave * 1152;
  const int sw = lm & 7;  // read-side swizzle term
  const f32x4 fzero = {0.f, 0.f, 0.f, 0.f};

  const int phase_end = pair;  // it 0..pair: qtile=pair; it pair+1..32: qtile=31-pair

  auto dma_tile = [&](int kt0, int buf) {
#pragma unroll
    for (int i = 0; i < 4; ++i) {  // K: [64 rows][128 u16], 16 rows/issue
      const int row = i * 16 + wave * 4 + (lane >> 4);
      const int cc = (lane & 15) ^ (row & 7);
      gl_lds16(&qkv[(b * 2048 + kt0 + row) * 6144 + 2048 + h * 128 + cc * 8],
               &Ks[buf][(i * 16 + wave * 4) * 128]);
    }
#pragma unroll
    for (int i = 0; i < 4; ++i) {  // V^T: [128 rows][64 u16], 32 rows/issue
      const int row = i * 32 + wave * 8 + (lane >> 3);
      const int cc = (lane & 7) ^ (row & 7);
      gl_lds16(&vt[bh * 262144 + row * 2048 + kt0 + cc * 8],
               &Vs[buf][(i * 32 + wave * 8) * 64]);
    }
  };

  dma_tile(0, 0);

  int qtile = pair;
  int qb = qtile * 64;
  int qrow = qb + wave * 16 + lm;
  int qoff = (b * 2048 + qrow) * 6144 + h * 128;
  s16x8 qfrag[4];
#pragma unroll
  for (int c = 0; c < 4; ++c)
    qfrag[c] = *(const s16x8*)&qkv[qoff + c * 32 + quad * 8];
  f32x4 o[8];
#pragma unroll
  for (int dt = 0; dt < 8; ++dt) o[dt] = fzero;
  float m_run = NEG_BIG, l_run = 0.f;

  __syncthreads();  // buf0 DMA drained

  for (int it = 0; it < 33; ++it) {
    const int kt0 = (it <= phase_end ? it : it - phase_end - 1) * 64;
    const int buf = it & 1;

    if (it < 32) {
      const int nkt = (it + 1 <= phase_end ? it + 1 : it - phase_end) * 64;
      dma_tile(nkt, buf ^ 1);
    }

    // ---- S^T = K * Q^T on buf ----
    f32x4 sa[4];
#pragma unroll
    for (int ss = 0; ss < 4; ++ss) sa[ss] = fzero;
#pragma unroll
    for (int ss = 0; ss < 4; ++ss)
#pragma unroll
      for (int c = 0; c < 4; ++c) {
        const int ccs = (c * 4 + quad) ^ sw;
        s16x8 a = *(const s16x8*)&Ks[buf][(ss * 16 + lm) * 128 + ccs * 8];
        sa[ss] = mfma16(a, qfrag[c], sa[ss]);
      }

    // ---- scale + causal mask + online softmax (per column q = lm) ----
    float p[4][4];
    float vmax = NEG_BIG;
#pragma unroll
    for (int ss = 0; ss < 4; ++ss)
#pragma unroll
      for (int r = 0; r < 4; ++r) {
        const int kg = kt0 + ss * 16 + quad * 4 + r;
        float v = sa[ss][r] * ATTN_SCALE;
        if (kg > qrow) v = NEG_BIG;
        p[ss][r] = v;
        vmax = fmaxf(vmax, v);
      }
    vmax = fmaxf(vmax, __shfl_xor(vmax, 16, 64));
    vmax = fmaxf(vmax, __shfl_xor(vmax, 32, 64));
    const float m_new = fmaxf(m_run, vmax);
    const float alpha = __expf(m_run - m_new);
    float rsum = 0.f;
#pragma unroll
    for (int ss = 0; ss < 4; ++ss)
#pragma unroll
      for (int r = 0; r < 4; ++r) {
        p[ss][r] = __expf(p[ss][r] - m_new);  // masked: exp(-huge) = 0
        rsum += p[ss][r];
      }
    rsum += __shfl_xor(rsum, 16, 64);
    rsum += __shfl_xor(rsum, 32, 64);
    l_run = l_run * alpha + rsum;
    m_run = m_new;
#pragma unroll
    for (int dt = 0; dt < 8; ++dt) o[dt] *= alpha;

    // ---- P -> wave-private LDS bounce ----
#pragma unroll
    for (int ss = 0; ss < 4; ++ss)
#pragma unroll
      for (int r = 0; r < 4; ++r)
        Ps[pbase + lm * 72 + ss * 16 + quad * 4 + r] = f2bf(p[ss][r]);
    const s16x8 pv0 = *(const s16x8*)&Ps[pbase + lm * 72 + quad * 8];
    const s16x8 pv1 = *(const s16x8*)&Ps[pbase + lm * 72 + 32 + quad * 8];

    // ---- O^T += V^T * P^T ----
#pragma unroll
    for (int dt = 0; dt < 8; ++dt) {
      const int c0 = (quad ^ sw) * 8, c1 = ((4 + quad) ^ sw) * 8;
      s16x8 a0 = *(const s16x8*)&Vs[buf][(dt * 16 + lm) * 64 + c0];
      s16x8 a1 = *(const s16x8*)&Vs[buf][(dt * 16 + lm) * 64 + c1];
      o[dt] = mfma16(a1, pv1, mfma16(a0, pv0, o[dt]));
    }

    if (it == phase_end) {
      const float inv_l = 1.0f / l_run;
#pragma unroll
      for (int dt = 0; dt < 8; ++dt)
#pragma unroll
        for (int r = 0; r < 4; ++r)
          qkv[qoff + dt * 16 + quad * 4 + r] = f2bf(o[dt][r] * inv_l);
      qtile = 31 - pair;
      qb = qtile * 64;
      qrow = qb + wave * 16 + lm;
      qoff = (b * 2048 + qrow) * 6144 + h * 128;
#pragma unroll
      for (int c = 0; c < 4; ++c)
        qfrag[c] = *(const s16x8*)&qkv[qoff + c * 32 + quad * 8];
#pragma unroll
      for (int dt = 0; dt < 8; ++dt) o[dt] = fzero;
      m_run = NEG_BIG; l_run = 0.f;
    }

    if (it < 32) __syncthreads();
  }

  const float inv_l = 1.0f / l_run;
#pragma unroll
  for (int dt = 0; dt < 8; ++dt)
#pragma unroll
    for (int r = 0; r < 4; ++r)
      qkv[qoff + dt * 16 + quad * 4 + r] = f2bf(o[dt][r] * inv_l);
}

// ---------------- host launcher ----------------------------------------
extern "C" void kernel_launch(void* const* d_in, const int* in_sizes, int n_in,
                              void* d_out, int out_size, void* d_ws, size_t ws_size,
                              hipStream_t stream) {
  const float* hidden = (const float*)d_in[0];  // [4096][2048] fp32
  const float* w_qkv  = (const float*)d_in[1];  // [2048][6144] fp32
  const float* w_o    = (const float*)d_in[2];  // [2048][2048] fp32
  float* out = (float*)d_out;                   // [4096][2048] fp32
  u16* ws = (u16*)d_ws;

  u16* qkv   = ws;
  u16* wqkvT = ws + 25165824;
  u16* vt    = ws + 25165824;
  u16* woT   = ws + 33554432;
  u16* hb    = ws + 37748736;
  const bool fast = ws_size >= (size_t)46137344 * 2;

  dim3 tb(32, 8);
  k_transpose_cast<<<dim3(192, 64), tb, 0, stream>>>(w_qkv, wqkvT, 2048, 6144);
  if (fast) {
    k_cast<<<8192, 256, 0, stream>>>(hidden, hb, 2097152);
    k_gemm256b<<<384, 512, 0, stream>>>(hb, 2048, wqkvT, 2048, qkv, 6144);
  } else {
    k_gemm_lds<true, u16><<<dim3(48, 32), 256, 0, stream>>>(hidden, 2048, wqkvT,
                                                            qkv, 6144, 2048);
  }
  k_rope<<<32768, 256, 0, stream>>>(qkv);
  k_vtrans<<<dim3(64, 4, 32), tb, 0, stream>>>(qkv, vt);
  k_transpose_cast<<<dim3(64, 64), tb, 0, stream>>>(w_o, woT, 2048, 2048);
  k_attn<<<dim3(32, 16), 256, 0, stream>>>(qkv, vt);  // x=bh (XCD locality)
  if (fast) {
    k_gemm256<float><<<256, 512, 0, stream>>>(qkv, 6144, woT, 2048, out, 2048);
  } else {
    k_gemm_lds<false, float><<<dim3(16, 32), 256, 0, stream>>>(qkv, 6144, woT,
                                                               out, 2048, 2048);
  }
}

// Round 8
// 410.098 us; speedup vs baseline: 1.0862x; 1.0862x over previous
//
#include <hip/hip_runtime.h>
#include <math.h>

typedef unsigned short u16;
typedef short s16x8 __attribute__((ext_vector_type(8)));  // 8 bf16 lanes (4 VGPRs)
typedef float f32x4 __attribute__((ext_vector_type(4)));

// B=2, S=2048, D=2048, H=16, HD=128; qkv row width = 6144
#define ATTN_SCALE 0.08838834764831845f
// ATTN_SCALE * log2(e): softmax done in exp2 domain (v_exp_f32 = 2^x)
#define ATTN_SC2 0.1275174245f
#define NEG_BIG -1.0e30f

__device__ __forceinline__ u16 f2bf(float f) {
  union { float f; unsigned u; } c; c.f = f;
  return (u16)((c.u + 0x7fffu + ((c.u >> 16) & 1u)) >> 16);  // RNE
}
__device__ __forceinline__ float bf2f(u16 v) {
  union { unsigned u; float f; } c; c.u = ((unsigned)v) << 16;
  return c.f;
}
__device__ __forceinline__ f32x4 mfma16(s16x8 a, s16x8 b, f32x4 c) {
  return __builtin_amdgcn_mfma_f32_16x16x32_bf16(a, b, c, 0, 0, 0);
}
// async global->LDS DMA, 16 B/lane; LDS dest = wave-uniform base + lane*16
__device__ __forceinline__ void gl_lds16(const u16* g, u16* l) {
  __builtin_amdgcn_global_load_lds(
      (const __attribute__((address_space(1))) unsigned int*)g,
      (__attribute__((address_space(3))) unsigned int*)l, 16, 0, 0);
}

// -------- fp32 -> bf16 elementwise cast (float4 vectorized) -------------
__global__ __launch_bounds__(256) void k_cast(const float* __restrict__ in,
                                              u16* __restrict__ out, int n4) {
  const int i = blockIdx.x * 256 + threadIdx.x;
  if (i >= n4) return;
  const float4 v = ((const float4*)in)[i];
  ushort4 o;
  o.x = f2bf(v.x); o.y = f2bf(v.y); o.z = f2bf(v.z); o.w = f2bf(v.w);
  ((ushort4*)out)[i] = o;
}

// -------- fp32 [R][C] -> bf16 out[C][R] transpose+cast ------------------
__global__ __launch_bounds__(256) void k_transpose_cast(const float* __restrict__ in,
                                                        u16* __restrict__ out,
                                                        int R, int C) {
  __shared__ __attribute__((aligned(16))) u16 tile[32][33];
  const int c0 = blockIdx.x * 32, r0 = blockIdx.y * 32;
  const int tx = threadIdx.x, ty = threadIdx.y;
#pragma unroll
  for (int i = 0; i < 4; ++i)
    tile[ty + 8 * i][tx] = f2bf(in[(r0 + ty + 8 * i) * C + c0 + tx]);
  __syncthreads();
#pragma unroll
  for (int i = 0; i < 4; ++i)
    out[(c0 + ty + 8 * i) * R + r0 + tx] = tile[tx][ty + 8 * i];
}

// ---------------- V -> V^T per (b,h): vt[bh][d][s] = qkv_v[b,s,h,d] ------
__global__ __launch_bounds__(256) void k_vtrans(const u16* __restrict__ qkv,
                                                u16* __restrict__ vt) {
  __shared__ __attribute__((aligned(16))) u16 tile[32][33];
  const int bh = blockIdx.z, b = bh >> 4, h = bh & 15;
  const int s0 = blockIdx.x * 32, d0 = blockIdx.y * 32;
  const int tx = threadIdx.x, ty = threadIdx.y;
#pragma unroll
  for (int i = 0; i < 4; ++i) {
    const int s = s0 + ty + 8 * i;
    tile[ty + 8 * i][tx] = qkv[(b * 2048 + s) * 6144 + 4096 + h * 128 + d0 + tx];
  }
  __syncthreads();
#pragma unroll
  for (int i = 0; i < 4; ++i) {
    const int d = d0 + ty + 8 * i;
    vt[bh * 262144 + d * 2048 + s0 + tx] = tile[tx][ty + 8 * i];
  }
}

// ---------------- RoPE in-place on Q and K sections of qkv (bf16) -------
__global__ __launch_bounds__(256) void k_rope(u16* __restrict__ qkv) {
  const int id = blockIdx.x * 256 + threadIdx.x;  // 8,388,608 threads
  const int j = id & 63;
  const int h = (id >> 6) & 15;
  const int sec = (id >> 10) & 1;
  const int m = id >> 11;  // b*2048+s
  const int s = m & 2047;
  const int base = m * 6144 + sec * 2048 + h * 128 + j;
  const float q0 = bf2f(qkv[base]);
  const float q1 = bf2f(qkv[base + 64]);
  const float inv = exp2f((float)j * -0.20762050593046014f);  // 10000^(-j/64)
  const float ang = (float)s * inv;
  float c, sn;
  sincosf(ang, &sn, &c);  // sincosf(x, SIN*, COS*) — sin FIRST
  qkv[base]      = f2bf(q0 * c - q1 * sn);
  qkv[base + 64] = f2bf(q1 * c + q0 * sn);
}

// ------- GEMM (m97 structure): C[M][N] = A[M][K] * BT[N][K]^T -----------
// kept for the fp32-A fallback path.
template <bool A_F32, typename OUT_T>
__global__ __launch_bounds__(256) void k_gemm_lds(const void* __restrict__ Ap, int lda,
                                                  const u16* __restrict__ BT,
                                                  OUT_T* __restrict__ C, int ldc,
                                                  int K) {
  __shared__ __attribute__((aligned(16))) u16 As[128 * 32];
  __shared__ __attribute__((aligned(16))) u16 Bs[128 * 32];
  const int tid = threadIdx.x;
  const int lane = tid & 63, wave = tid >> 6;
  const int lm = lane & 15, quad = lane >> 4;
  const int wm = wave >> 1, wn = wave & 1;
  const int m0 = blockIdx.y * 128, n0 = blockIdx.x * 128;
  const int srow = lane >> 2, scol = (lane & 3) * 8;  // staging map

  const f32x4 fzero = {0.f, 0.f, 0.f, 0.f};
  f32x4 acc[4][4];
#pragma unroll
  for (int i = 0; i < 4; ++i)
#pragma unroll
    for (int j = 0; j < 4; ++j) acc[i][j] = fzero;

  for (int k0 = 0; k0 < K; k0 += 32) {
    __syncthreads();
    if constexpr (A_F32) {
      const float* Af = (const float*)Ap;
#pragma unroll
      for (int i = 0; i < 2; ++i) {
        const int seg = tid + 256 * i;
        const int row = seg >> 2, c8 = (seg & 3) * 8;
        const float4 u = *(const float4*)&Af[(m0 + row) * lda + k0 + c8];
        const float4 w = *(const float4*)&Af[(m0 + row) * lda + k0 + c8 + 4];
        uint4 pk;
        pk.x = (unsigned)f2bf(u.x) | ((unsigned)f2bf(u.y) << 16);
        pk.y = (unsigned)f2bf(u.z) | ((unsigned)f2bf(u.w) << 16);
        pk.z = (unsigned)f2bf(w.x) | ((unsigned)f2bf(w.y) << 16);
        pk.w = (unsigned)f2bf(w.z) | ((unsigned)f2bf(w.w) << 16);
        *(uint4*)&As[row * 32 + c8] = pk;
      }
#pragma unroll
      for (int j = 0; j < 2; ++j) {
        const int rb = wave * 32 + j * 16;
        gl_lds16(&BT[(n0 + rb + srow) * K + k0 + scol], &Bs[rb * 32]);
      }
    } else {
      const u16* Ab = (const u16*)Ap;
#pragma unroll
      for (int j = 0; j < 2; ++j) {
        const int rb = wave * 32 + j * 16;
        gl_lds16(&Ab[(m0 + rb + srow) * lda + k0 + scol], &As[rb * 32]);
        gl_lds16(&BT[(n0 + rb + srow) * K + k0 + scol], &Bs[rb * 32]);
      }
    }
    __syncthreads();  // drains vmcnt (DMA) + lgkmcnt before reads

    s16x8 af[4], bfr[4];
#pragma unroll
    for (int t = 0; t < 4; ++t) {
      af[t]  = *(const s16x8*)&As[(wm * 64 + t * 16 + lm) * 32 + quad * 8];
      bfr[t] = *(const s16x8*)&Bs[(wn * 64 + t * 16 + lm) * 32 + quad * 8];
    }
#pragma unroll
    for (int mt = 0; mt < 4; ++mt)
#pragma unroll
      for (int nt = 0; nt < 4; ++nt)
        acc[mt][nt] = mfma16(af[mt], bfr[nt], acc[mt][nt]);
  }
#pragma unroll
  for (int mt = 0; mt < 4; ++mt)
#pragma unroll
    for (int nt = 0; nt < 4; ++nt)
#pragma unroll
      for (int r = 0; r < 4; ++r) {
        const float v = acc[mt][nt][r];
        const int idx = (m0 + wm * 64 + mt * 16 + quad * 4 + r) * ldc +
                        n0 + wn * 64 + nt * 16 + lm;
        if constexpr (sizeof(OUT_T) == 2) C[idx] = f2bf(v);
        else                              C[idx] = v;
      }
}

// ------- 256x128 GEMM v4 (3-deep rotating pipeline) — best measured -----
// 135.8 us QKV @ grid 768 (zero tail), MfmaUtil 32.2 (round 6).
template <typename OUT_T>
__global__ __launch_bounds__(512, 2) void k_gemm256(const u16* __restrict__ A, int lda,
                                                    const u16* __restrict__ BT, int ldb,
                                                    OUT_T* __restrict__ C, int ldc) {
  __shared__ __attribute__((aligned(16))) u16 As[3][2][256 * 32];  // 96 KB
  __shared__ __attribute__((aligned(16))) u16 Bs[3][2][128 * 32];  // 48 KB
  const int tid = threadIdx.x;
  const int lane = tid & 63, wave = tid >> 6;
  const int lm = lane & 15, quad = lane >> 4;
  const int wm = wave >> 1, wn = wave & 1;  // 4M x 2N wave grid

  int bid = (blockIdx.x & 7) * (gridDim.x >> 3) + (blockIdx.x >> 3);
  const int m0 = (bid & 15) * 256;  // M=4096 -> 16 tiles
  const int n0 = (bid >> 4) * 128;

  const int srow = lane >> 2, schunk = (lane & 3) * 8;
  auto stage_h = [&](int t, int h) {
    const int bi = t % 3;
    const int k0 = t * 64 + h * 32 + schunk;
    gl_lds16(&BT[(n0 + wave * 16 + srow) * ldb + k0],
             &Bs[bi][h][(wave * 16) * 32]);
    gl_lds16(&A[(m0 + wave * 32 + srow) * lda + k0],
             &As[bi][h][(wave * 32) * 32]);
    gl_lds16(&A[(m0 + wave * 32 + 16 + srow) * lda + k0],
             &As[bi][h][(wave * 32 + 16) * 32]);
  };

  const f32x4 fzero = {0.f, 0.f, 0.f, 0.f};
  f32x4 acc[4][4];
#pragma unroll
  for (int i = 0; i < 4; ++i)
#pragma unroll
    for (int j = 0; j < 4; ++j) acc[i][j] = fzero;

  stage_h(0, 0); stage_h(0, 1); stage_h(1, 0); stage_h(1, 1);
  asm volatile("s_waitcnt vmcnt(9)" ::: "memory");
  asm volatile("s_barrier" ::: "memory");

  for (int c = 0; c < 32; ++c) {
    const int bi = c % 3;
#pragma unroll
    for (int p = 0; p < 2; ++p) {
      s16x8 bfr[4], afr[4];
#pragma unroll
      for (int nt = 0; nt < 4; ++nt)
        bfr[nt] = *(const s16x8*)
            &Bs[bi][p][(wn * 64 + nt * 16 + lm) * 32 + quad * 8];
#pragma unroll
      for (int i = 0; i < 4; ++i)
        afr[i] = *(const s16x8*)
            &As[bi][p][(wm * 64 + i * 16 + lm) * 32 + quad * 8];
      if (c < 30) stage_h(c + 2, p);
      if (c < 30) {
        asm volatile("s_waitcnt vmcnt(9)" ::: "memory");
      } else if (c == 30) {
        if (p == 0) asm volatile("s_waitcnt vmcnt(6)" ::: "memory");
        else        asm volatile("s_waitcnt vmcnt(3)" ::: "memory");
      } else {
        if (p == 0) asm volatile("s_waitcnt vmcnt(0)" ::: "memory");
      }
      asm volatile("s_barrier" ::: "memory");
      __builtin_amdgcn_s_setprio(1);
#pragma unroll
      for (int i = 0; i < 4; ++i)
#pragma unroll
        for (int nt = 0; nt < 4; ++nt)
          acc[i][nt] = mfma16(afr[i], bfr[nt], acc[i][nt]);
      __builtin_amdgcn_s_setprio(0);
      if (!(c == 31 && p == 1)) asm volatile("s_barrier" ::: "memory");
    }
  }

#pragma unroll
  for (int i = 0; i < 4; ++i)
#pragma unroll
    for (int nt = 0; nt < 4; ++nt)
#pragma unroll
      for (int r = 0; r < 4; ++r) {
        const float v = acc[i][nt][r];
        const int idx = (m0 + wm * 64 + i * 16 + quad * 4 + r) * ldc +
                        n0 + wn * 64 + nt * 16 + lm;
        if constexpr (sizeof(OUT_T) == 2) C[idx] = f2bf(v);
        else                              C[idx] = v;
      }
}

// ---------------- causal flash attention, v5 ----------------------------
// v4 structure (64-key tiles, causal pairing, DMA dbuf, 1 barrier/iter,
// XOR-swizzled LDS) + VALU cuts: log2-domain softmax (exp2f = bare
// v_exp_f32), T13 rescale-skip at THR=0 (bit-identical: alpha=1 when max
// doesn't grow, fires ~85% of iters), v_cvt_pk_bf16_f32 packed P
// conversion (RNE, same as f2bf), wave-uniform mask-skip on fully
// unmasked tiles.
__global__ __launch_bounds__(256) void k_attn(u16* __restrict__ qkv,
                                              const u16* __restrict__ vt) {
  __shared__ __attribute__((aligned(16))) u16 Ks[2][64 * 128];  // 2x16 KB, swizzled
  __shared__ __attribute__((aligned(16))) u16 Vs[2][128 * 64];  // 2x16 KB, swizzled
  __shared__ __attribute__((aligned(16))) u16 Ps[4 * 16 * 72];  //    9 KB
  const int bh = blockIdx.x, pair = blockIdx.y;
  const int b = bh >> 4, h = bh & 15;
  const int tid = threadIdx.x;
  const int lane = tid & 63, wave = tid >> 6;
  const int lm = lane & 15, quad = lane >> 4;
  const int pbase = wave * 1152;
  const int sw = lm & 7;  // read-side swizzle term
  const f32x4 fzero = {0.f, 0.f, 0.f, 0.f};

  const int phase_end = pair;  // it 0..pair: qtile=pair; it pair+1..32: qtile=31-pair

  auto dma_tile = [&](int kt0, int buf) {
#pragma unroll
    for (int i = 0; i < 4; ++i) {  // K: [64 rows][128 u16], 16 rows/issue
      const int row = i * 16 + wave * 4 + (lane >> 4);
      const int cc = (lane & 15) ^ (row & 7);
      gl_lds16(&qkv[(b * 2048 + kt0 + row) * 6144 + 2048 + h * 128 + cc * 8],
               &Ks[buf][(i * 16 + wave * 4) * 128]);
    }
#pragma unroll
    for (int i = 0; i < 4; ++i) {  // V^T: [128 rows][64 u16], 32 rows/issue
      const int row = i * 32 + wave * 8 + (lane >> 3);
      const int cc = (lane & 7) ^ (row & 7);
      gl_lds16(&vt[bh * 262144 + row * 2048 + kt0 + cc * 8],
               &Vs[buf][(i * 32 + wave * 8) * 64]);
    }
  };

  dma_tile(0, 0);

  int qtile = pair;
  int qb = qtile * 64;
  int qrow = qb + wave * 16 + lm;
  int qoff = (b * 2048 + qrow) * 6144 + h * 128;
  s16x8 qfrag[4];
#pragma unroll
  for (int c = 0; c < 4; ++c)
    qfrag[c] = *(const s16x8*)&qkv[qoff + c * 32 + quad * 8];
  f32x4 o[8];
#pragma unroll
  for (int dt = 0; dt < 8; ++dt) o[dt] = fzero;
  float m_run = NEG_BIG, l_run = 0.f;

  __syncthreads();  // buf0 DMA drained

  for (int it = 0; it < 33; ++it) {
    const int kt0 = (it <= phase_end ? it : it - phase_end - 1) * 64;
    const int buf = it & 1;

    if (it < 32) {
      const int nkt = (it + 1 <= phase_end ? it + 1 : it - phase_end) * 64;
      dma_tile(nkt, buf ^ 1);
    }

    // ---- S^T = K * Q^T on buf ----
    f32x4 sa[4];
#pragma unroll
    for (int ss = 0; ss < 4; ++ss) sa[ss] = fzero;
#pragma unroll
    for (int ss = 0; ss < 4; ++ss)
#pragma unroll
      for (int c = 0; c < 4; ++c) {
        const int ccs = (c * 4 + quad) ^ sw;
        s16x8 a = *(const s16x8*)&Ks[buf][(ss * 16 + lm) * 128 + ccs * 8];
        sa[ss] = mfma16(a, qfrag[c], sa[ss]);
      }

    // ---- scale + causal mask + online softmax (log2 domain, col q=lm) --
    float p[4][4];
    float vmax = NEG_BIG;
    if (kt0 + 63 > qrow - lm) {  // wave-uniform: some lane needs masking
#pragma unroll
      for (int ss = 0; ss < 4; ++ss)
#pragma unroll
        for (int r = 0; r < 4; ++r) {
          const int kg = kt0 + ss * 16 + quad * 4 + r;
          float v = sa[ss][r] * ATTN_SC2;
          if (kg > qrow) v = NEG_BIG;
          p[ss][r] = v;
          vmax = fmaxf(vmax, v);
        }
    } else {                     // tile fully below the diagonal
#pragma unroll
      for (int ss = 0; ss < 4; ++ss)
#pragma unroll
        for (int r = 0; r < 4; ++r) {
          const float v = sa[ss][r] * ATTN_SC2;
          p[ss][r] = v;
          vmax = fmaxf(vmax, v);
        }
    }
    vmax = fmaxf(vmax, __shfl_xor(vmax, 16, 64));
    vmax = fmaxf(vmax, __shfl_xor(vmax, 32, 64));
    // T13 @ THR=0: when no column's max grows, alpha==1 exactly -> skip.
    if (!__all(vmax <= m_run)) {
      const float m_new = fmaxf(m_run, vmax);
      const float alpha = exp2f(m_run - m_new);
      l_run *= alpha;
#pragma unroll
      for (int dt = 0; dt < 8; ++dt) o[dt] *= alpha;
      m_run = m_new;
    }
    float rsum = 0.f;
#pragma unroll
    for (int ss = 0; ss < 4; ++ss)
#pragma unroll
      for (int r = 0; r < 4; ++r) {
        p[ss][r] = exp2f(p[ss][r] - m_run);  // masked: exp2(-huge) = 0
        rsum += p[ss][r];
      }
    rsum += __shfl_xor(rsum, 16, 64);
    rsum += __shfl_xor(rsum, 32, 64);
    l_run += rsum;

    // ---- P -> wave-private LDS bounce (packed bf16 cvt, u32 writes) ----
#pragma unroll
    for (int ss = 0; ss < 4; ++ss)
#pragma unroll
      for (int rp = 0; rp < 2; ++rp) {
        unsigned pk;
        asm("v_cvt_pk_bf16_f32 %0, %1, %2"
            : "=v"(pk) : "v"(p[ss][rp * 2]), "v"(p[ss][rp * 2 + 1]));
        *(unsigned*)&Ps[pbase + lm * 72 + ss * 16 + quad * 4 + rp * 2] = pk;
      }
    const s16x8 pv0 = *(const s16x8*)&Ps[pbase + lm * 72 + quad * 8];
    const s16x8 pv1 = *(const s16x8*)&Ps[pbase + lm * 72 + 32 + quad * 8];

    // ---- O^T += V^T * P^T ----
#pragma unroll
    for (int dt = 0; dt < 8; ++dt) {
      const int c0 = (quad ^ sw) * 8, c1 = ((4 + quad) ^ sw) * 8;
      s16x8 a0 = *(const s16x8*)&Vs[buf][(dt * 16 + lm) * 64 + c0];
      s16x8 a1 = *(const s16x8*)&Vs[buf][(dt * 16 + lm) * 64 + c1];
      o[dt] = mfma16(a1, pv1, mfma16(a0, pv0, o[dt]));
    }

    if (it == phase_end) {
      const float inv_l = 1.0f / l_run;
#pragma unroll
      for (int dt = 0; dt < 8; ++dt)
#pragma unroll
        for (int r = 0; r < 4; ++r)
          qkv[qoff + dt * 16 + quad * 4 + r] = f2bf(o[dt][r] * inv_l);
      qtile = 31 - pair;
      qb = qtile * 64;
      qrow = qb + wave * 16 + lm;
      qoff = (b * 2048 + qrow) * 6144 + h * 128;
#pragma unroll
      for (int c = 0; c < 4; ++c)
        qfrag[c] = *(const s16x8*)&qkv[qoff + c * 32 + quad * 8];
#pragma unroll
      for (int dt = 0; dt < 8; ++dt) o[dt] = fzero;
      m_run = NEG_BIG; l_run = 0.f;
    }

    if (it < 32) __syncthreads();
  }

  const float inv_l = 1.0f / l_run;
#pragma unroll
  for (int dt = 0; dt < 8; ++dt)
#pragma unroll
    for (int r = 0; r < 4; ++r)
      qkv[qoff + dt * 16 + quad * 4 + r] = f2bf(o[dt][r] * inv_l);
}

// ---------------- host launcher ----------------------------------------
extern "C" void kernel_launch(void* const* d_in, const int* in_sizes, int n_in,
                              void* d_out, int out_size, void* d_ws, size_t ws_size,
                              hipStream_t stream) {
  const float* hidden = (const float*)d_in[0];  // [4096][2048] fp32
  const float* w_qkv  = (const float*)d_in[1];  // [2048][6144] fp32
  const float* w_o    = (const float*)d_in[2];  // [2048][2048] fp32
  float* out = (float*)d_out;                   // [4096][2048] fp32
  u16* ws = (u16*)d_ws;

  u16* qkv   = ws;
  u16* wqkvT = ws + 25165824;
  u16* vt    = ws + 25165824;
  u16* woT   = ws + 33554432;
  u16* hb    = ws + 37748736;
  const bool fast = ws_size >= (size_t)46137344 * 2;

  dim3 tb(32, 8);
  k_transpose_cast<<<dim3(192, 64), tb, 0, stream>>>(w_qkv, wqkvT, 2048, 6144);
  if (fast) {
    k_cast<<<8192, 256, 0, stream>>>(hidden, hb, 2097152);
    k_gemm256<u16><<<768, 512, 0, stream>>>(hb, 2048, wqkvT, 2048, qkv, 6144);
  } else {
    k_gemm_lds<true, u16><<<dim3(48, 32), 256, 0, stream>>>(hidden, 2048, wqkvT,
                                                            qkv, 6144, 2048);
  }
  k_rope<<<32768, 256, 0, stream>>>(qkv);
  k_vtrans<<<dim3(64, 4, 32), tb, 0, stream>>>(qkv, vt);
  k_transpose_cast<<<dim3(64, 64), tb, 0, stream>>>(w_o, woT, 2048, 2048);
  k_attn<<<dim3(32, 16), 256, 0, stream>>>(qkv, vt);  // x=bh (XCD locality)
  if (fast) {
    k_gemm256<float><<<256, 512, 0, stream>>>(qkv, 6144, woT, 2048, out, 2048);
  } else {
    k_gemm_lds<false, float><<<dim3(16, 32), 256, 0, stream>>>(qkv, 6144, woT,
                                                               out, 2048, 2048);
  }
}